// Round 1
// baseline (301.102 us; speedup 1.0000x reference)
//
#include <hip/hip_runtime.h>
#include <stdint.h>

#define NB 64
#define SEQL 512
#define L 510
#define T 9
#define H 768

__device__ __forceinline__ float rl(float v, int l) {
  return __uint_as_float(__builtin_amdgcn_readlane(__float_as_uint(v), l));
}

// ---------------- Kernel 1: emissions = hidden[:,1:-1,:] @ weight^T + bias ----
// wave-per-row, lane-on-K. weight staged in LDS (27.6 KB).
__global__ __launch_bounds__(256) void emis_kernel(
    const float* __restrict__ hidden, const float* __restrict__ weight,
    const float* __restrict__ bias, float* __restrict__ em) {
  __shared__ float4 wl[T * 192];  // 9 x 768 floats
  const float4* w4 = (const float4*)weight;
  for (int k = threadIdx.x; k < T * 192; k += 256) wl[k] = w4[k];
  __syncthreads();
  const int lane = threadIdx.x & 63;
  const int r = blockIdx.x * 4 + (threadIdx.x >> 6);  // row in [0, 32640)
  const int b = r / L;
  const int l = r - b * L;
  const float4* h4 = (const float4*)(hidden + ((size_t)(b * SEQL + l + 1)) * H);
  float acc[T];
#pragma unroll
  for (int t = 0; t < T; ++t) acc[t] = 0.f;
#pragma unroll
  for (int k = 0; k < 3; ++k) {
    float4 h = h4[lane + 64 * k];
#pragma unroll
    for (int t = 0; t < T; ++t) {
      float4 w = wl[t * 192 + lane + 64 * k];
      acc[t] = fmaf(h.x, w.x, fmaf(h.y, w.y, fmaf(h.z, w.z, fmaf(h.w, w.w, acc[t]))));
    }
  }
#pragma unroll
  for (int off = 32; off; off >>= 1) {
#pragma unroll
    for (int t = 0; t < T; ++t) acc[t] += __shfl_xor(acc[t], off);
  }
  if (lane == 0) {
#pragma unroll
    for (int t = 0; t < T; ++t) em[(size_t)r * T + t] = acc[t] + bias[t];
  }
}

// ---------------- Kernel 2: per-batch CRF (denominator + numerator + viterbi) -
// block = 128 (2 waves). wave0: scaled-linear-domain forward alpha scan.
// wave1: viterbi max-plus scan + history. Numerator computed in parallel phase.
__global__ __launch_bounds__(128) void crf_kernel(
    const float* __restrict__ em, const int* __restrict__ labels,
    const float* __restrict__ start_t, const float* __restrict__ end_t,
    const float* __restrict__ trans, float* __restrict__ out,
    float* __restrict__ llh) {
  __shared__ float s_em[L * T];             // 18360 B
  __shared__ uint32_t s_hist[(L - 1) * 3];  // byte-packed hist, stride 12 B/step
  __shared__ int s_tags[L];
  __shared__ int s_out[L];
  __shared__ float s_trans[81];
  __shared__ float s_start[T];
  __shared__ float s_end[T];
  __shared__ float s_num[2];

  const int b = blockIdx.x;
  const int tid = threadIdx.x;
  const float* emrow = em + (size_t)b * (L * T);

  for (int k = tid; k < L * T; k += 128) s_em[k] = emrow[k];
  for (int k = tid; k < L; k += 128) s_tags[k] = labels[b * SEQL + 1 + k];
  if (tid < 81) s_trans[tid] = trans[tid];
  if (tid < T) { s_start[tid] = start_t[tid]; s_end[tid] = end_t[tid]; }
  __syncthreads();

  const int lane = tid & 63;
  const int jj = lane < T ? lane : T - 1;
  const bool valid = lane < T;

  // ---- numerator: parallel over l (tags independent of scan state) ----
  {
    float part = 0.f;
    for (int l = 1 + tid; l < L; l += 128) {
      int raw = s_tags[l];
      if (raw >= 0) {
        int p = l - 1;
        while (p >= 1 && s_tags[p] < 0) --p;
        int pt;
        if (p >= 1) pt = s_tags[p];
        else { int r0 = s_tags[0]; pt = (r0 >= 0) ? r0 : 0; }
        part += s_trans[pt * 9 + raw] + s_em[l * 9 + raw];
      }
    }
#pragma unroll
    for (int off = 32; off; off >>= 1) part += __shfl_xor(part, off);
    if (lane == 0) s_num[tid >> 6] = part;
  }
  __syncthreads();

  int last = 0;  // viterbi last tag (set by wave 1)

  if (tid < 64) {
    // ================= wave 0: denominator, scaled linear domain ============
    float Ecol[T];
#pragma unroll
    for (int i = 0; i < T; ++i) Ecol[i] = __expf(s_trans[i * 9 + jj]);
    float em0 = s_em[jj];
    float alpha0 = valid ? (s_start[jj] + em0) : -1e30f;
    float C = alpha0;
    C = fmaxf(C, __shfl_xor(C, 1));
    C = fmaxf(C, __shfl_xor(C, 2));
    C = fmaxf(C, __shfl_xor(C, 4));
    C = fmaxf(C, __shfl_xor(C, 8));
    float A = valid ? __expf(alpha0 - C) : 0.f;

    for (int l = 1; l < L; ++l) {
      float emj = s_em[l * 9 + jj];
      bool m = s_tags[l] >= 0;
      float a0 = 0.f, a1 = 0.f, a2 = 0.f;
#pragma unroll
      for (int i = 0; i < 3; ++i) {
        a0 = fmaf(rl(A, i), Ecol[i], a0);
        a1 = fmaf(rl(A, i + 3), Ecol[i + 3], a1);
        a2 = fmaf(rl(A, i + 6), Ecol[i + 6], a2);
      }
      float An = (a0 + a1 + a2) * __expf(emj);
      A = (m && valid) ? An : A;
      if ((l & 7) == 0) {  // rescale: keep A in range
        float s = A;
        s = fmaxf(s, __shfl_xor(s, 1));
        s = fmaxf(s, __shfl_xor(s, 2));
        s = fmaxf(s, __shfl_xor(s, 4));
        s = fmaxf(s, __shfl_xor(s, 8));
        A = A / s;
        C += __logf(s);
      }
    }
    float fe = valid ? (A * __expf(s_end[jj])) : 0.f;
    fe += __shfl_xor(fe, 1);
    fe += __shfl_xor(fe, 2);
    fe += __shfl_xor(fe, 4);
    fe += __shfl_xor(fe, 8);
    float den = __logf(fe) + C;

    if (lane == 0) {
      // numerator assembly
      int r0 = s_tags[0];
      int tag0 = (r0 >= 0) ? r0 : 0;
      float score0 = s_start[tag0] + s_em[tag0];
      int q = L - 1;
      while (q >= 1 && s_tags[q] < 0) --q;
      int lastt = (q >= 1) ? s_tags[q] : tag0;
      float numerator = score0 + s_num[0] + s_num[1] + s_end[lastt];
      llh[b] = numerator - den;
    }
  } else {
    // ================= wave 1: viterbi forward ==============================
    float tcol[T];
#pragma unroll
    for (int i = 0; i < T; ++i) tcol[i] = s_trans[i * 9 + jj];
    float score = valid ? (s_start[jj] + s_em[jj]) : -1e30f;
    unsigned char* h8 = (unsigned char*)s_hist;

    for (int l = 1; l < L; ++l) {
      float emj = s_em[l * 9 + jj];
      bool m = s_tags[l] >= 0;
      float v[9];
#pragma unroll
      for (int i = 0; i < 9; ++i) v[i] = rl(score, i) + tcol[i];
      // first-argmax tournament (strict >, lower index wins ties)
      float b0v = v[0]; int b0i = 0; if (v[1] > b0v) { b0v = v[1]; b0i = 1; }
      float b1v = v[2]; int b1i = 2; if (v[3] > b1v) { b1v = v[3]; b1i = 3; }
      float b2v = v[4]; int b2i = 4; if (v[5] > b2v) { b2v = v[5]; b2i = 5; }
      float b3v = v[6]; int b3i = 6; if (v[7] > b3v) { b3v = v[7]; b3i = 7; }
      if (b1v > b0v) { b0v = b1v; b0i = b1i; }
      if (b3v > b2v) { b2v = b3v; b2i = b3i; }
      if (b2v > b0v) { b0v = b2v; b0i = b2i; }
      if (v[8] > b0v) { b0v = v[8]; b0i = 8; }
      float ns = b0v + emj;
      score = m ? ns : score;
      int hb = m ? b0i : jj;  // identity on masked steps
      if (valid) h8[(l - 1) * 12 + lane] = (unsigned char)hb;
    }
    float fv = valid ? (score + s_end[jj]) : -1e30f;
    float bv = rl(fv, 0); int bi = 0;
#pragma unroll
    for (int i = 1; i < 9; ++i) { float vv = rl(fv, i); if (vv > bv) { bv = vv; bi = i; } }
    last = bi;
  }
  __syncthreads();

  // ---- backtrack (thread 64 = wave1 lane0, holds `last`) ----
  if (tid == 64) {
    int cur = last;
    for (int s = L - 2; s >= 0; --s) {
      s_out[s + 1] = cur;
      uint32_t d0 = s_hist[s * 3], d1 = s_hist[s * 3 + 1], d2 = s_hist[s * 3 + 2];
      uint32_t w = (cur < 4) ? d0 : ((cur < 8) ? d1 : d2);
      cur = (int)((w >> (8 * (cur & 3))) & 0xffu);
    }
    s_out[0] = cur;
  }
  __syncthreads();

  for (int k = tid; k < L; k += 128) {
    out[1 + (size_t)b * L + k] = (s_tags[k] >= 0) ? (float)s_out[k] : 0.f;
  }
}

// ---------------- Kernel 3: reduce per-batch llh -> out[0] = -sum ------------
__global__ __launch_bounds__(64) void reduce_kernel(const float* __restrict__ llh,
                                                    float* __restrict__ out) {
  float v = llh[threadIdx.x];
#pragma unroll
  for (int off = 32; off; off >>= 1) v += __shfl_xor(v, off);
  if (threadIdx.x == 0) out[0] = -v;
}

extern "C" void kernel_launch(void* const* d_in, const int* in_sizes, int n_in,
                              void* d_out, int out_size, void* d_ws, size_t ws_size,
                              hipStream_t stream) {
  const float* hidden  = (const float*)d_in[0];
  const int*   labels  = (const int*)d_in[1];
  const float* weight  = (const float*)d_in[2];
  const float* bias    = (const float*)d_in[3];
  const float* start_t = (const float*)d_in[4];
  const float* end_t   = (const float*)d_in[5];
  const float* trans   = (const float*)d_in[6];
  float* out = (float*)d_out;

  float* em  = (float*)d_ws;                    // 64*510*9 floats = 1.175 MB
  float* llh = em + (size_t)NB * L * T;         // 64 floats

  emis_kernel<<<NB * L / 4, 256, 0, stream>>>(hidden, weight, bias, em);
  crf_kernel<<<NB, 128, 0, stream>>>(em, labels, start_t, end_t, trans, out, llh);
  reduce_kernel<<<1, 64, 0, stream>>>(llh, out);
}